// Round 2
// baseline (1233.364 us; speedup 1.0000x reference)
//
#include <hip/hip_runtime.h>
#include <cstddef>

// Problem constants (from reference):
//   x:[B,N,NX] fp32, c_attn_w:[NX,3NX], c_attn_b:[3NX], c_proj_w:[NX,NX], c_proj_b:[NX]
//   mask input (d_in[5]) is the causal mask ~tril -> applied analytically, input ignored.
// Outputs concatenated flat: a:[B,N,NX] (4,194,304 f32) then present:[2,B,H,N,hd] (8,388,608 f32).
#define NX_ 1024
#define NH_ 16
#define HD_ 64
#define B_  2
#define N_  2048
#define M_  (B_ * N_)   // 4096

// ---------------------------------------------------------------------------
// Tiled fp32 GEMM: out = A[M,1024] @ W[1024,NOUT] + bias
// BM=BN=128, BK=16, 256 threads (16x16), 8x8 per-thread microtile.
// MODE 0: qkv epilogue -> scatter q to out0 ([B,H,N,hd] ws), k to out1, v to out2 (present)
// MODE 1: plain row-major out0 [M,NOUT]
template<int NOUT, int MODE>
__global__ __launch_bounds__(256, 2)
void gemm_f32(const float* __restrict__ A, const float* __restrict__ W,
              const float* __restrict__ bias, float* __restrict__ out0,
              float* __restrict__ out1, float* __restrict__ out2)
{
    __shared__ float As[16][132];   // [k][m], pad 132 -> 2-way max on transpose store
    __shared__ float Bs[16][132];   // [k][n]
    const int t  = threadIdx.x;
    const int tx = t & 15, ty = t >> 4;
    const int m0 = blockIdx.y * 128;
    const int j0 = blockIdx.x * 128;

    float acc[8][8];
#pragma unroll
    for (int i = 0; i < 8; i++)
#pragma unroll
        for (int j = 0; j < 8; j++) acc[i][j] = 0.f;

    const int lar = t >> 1;          // A tile row 0..127 (2 threads/row)
    const int lac = (t & 1) * 8;     // A tile col 0 or 8
    const int lbr = t >> 4;          // B tile row 0..15
    const int lbc = (t & 15) * 8;    // B tile col (16 threads/row)

    const float* Ap = A + (size_t)(m0 + lar) * 1024 + lac;
    const float* Wp = W + (size_t)lbr * NOUT + j0 + lbc;

    float4 a0 = *(const float4*)(Ap);
    float4 a1 = *(const float4*)(Ap + 4);
    float4 b0 = *(const float4*)(Wp);
    float4 b1 = *(const float4*)(Wp + 4);

    for (int k0 = 0; k0 < 1024; k0 += 16) {
        __syncthreads();
        As[lac + 0][lar] = a0.x; As[lac + 1][lar] = a0.y;
        As[lac + 2][lar] = a0.z; As[lac + 3][lar] = a0.w;
        As[lac + 4][lar] = a1.x; As[lac + 5][lar] = a1.y;
        As[lac + 6][lar] = a1.z; As[lac + 7][lar] = a1.w;
        *(float4*)&Bs[lbr][lbc]     = b0;
        *(float4*)&Bs[lbr][lbc + 4] = b1;
        __syncthreads();
        if (k0 + 16 < 1024) {   // register prefetch of next K-slab overlaps compute below
            a0 = *(const float4*)(Ap + k0 + 16);
            a1 = *(const float4*)(Ap + k0 + 20);
            b0 = *(const float4*)(Wp + (size_t)(k0 + 16) * NOUT);
            b1 = *(const float4*)(Wp + (size_t)(k0 + 16) * NOUT + 4);
        }
#pragma unroll
        for (int kk = 0; kk < 16; kk++) {
            float av[8], bv[8];
            *(float4*)&av[0] = *(const float4*)&As[kk][ty * 8];
            *(float4*)&av[4] = *(const float4*)&As[kk][ty * 8 + 4];
            *(float4*)&bv[0] = *(const float4*)&Bs[kk][tx * 8];
            *(float4*)&bv[4] = *(const float4*)&Bs[kk][tx * 8 + 4];
#pragma unroll
            for (int i = 0; i < 8; i++)
#pragma unroll
                for (int j = 0; j < 8; j++)
                    acc[i][j] = fmaf(av[i], bv[j], acc[i][j]);
        }
    }

    const int jb = j0 + tx * 8;      // 8 output cols, never straddles 64/1024 boundaries
    float bz[8];
    *(float4*)&bz[0] = *(const float4*)(bias + jb);
    *(float4*)&bz[4] = *(const float4*)(bias + jb + 4);

    if (MODE == 1) {
#pragma unroll
        for (int i = 0; i < 8; i++) {
            const int gm = m0 + ty * 8 + i;
            float4 v0, v1;
            v0.x = acc[i][0] + bz[0]; v0.y = acc[i][1] + bz[1];
            v0.z = acc[i][2] + bz[2]; v0.w = acc[i][3] + bz[3];
            v1.x = acc[i][4] + bz[4]; v1.y = acc[i][5] + bz[5];
            v1.z = acc[i][6] + bz[6]; v1.w = acc[i][7] + bz[7];
            *(float4*)(out0 + (size_t)gm * NOUT + jb)     = v0;
            *(float4*)(out0 + (size_t)gm * NOUT + jb + 4) = v1;
        }
    } else {
        const int sec  = jb >> 10;       // 0=q, 1=k, 2=v
        const int jloc = jb & 1023;
        const int h    = jloc >> 6;
        const int d    = jloc & 63;
        float* dst = (sec == 0) ? out0 : (sec == 1) ? out1 : out2;
#pragma unroll
        for (int i = 0; i < 8; i++) {
            const int gm = m0 + ty * 8 + i;
            const int b  = gm >> 11;
            const int n  = gm & 2047;
            const size_t off = ((size_t)(b * NH_ + h) * N_ + n) * HD_ + d;
            float4 v0, v1;
            v0.x = acc[i][0] + bz[0]; v0.y = acc[i][1] + bz[1];
            v0.z = acc[i][2] + bz[2]; v0.w = acc[i][3] + bz[3];
            v1.x = acc[i][4] + bz[4]; v1.y = acc[i][5] + bz[5];
            v1.z = acc[i][6] + bz[6]; v1.w = acc[i][7] + bz[7];
            *(float4*)(dst + off)     = v0;
            *(float4*)(dst + off + 4) = v1;
        }
    }
}

// ---------------------------------------------------------------------------
// Flash-style fused causal attention, fp32 vector math.
// Block = one (b,h,q-tile of 64 rows). 256 threads (16x16), 4x4 S/O microtile.
// K/V LDS rows are XOR-swizzled in float4 slots (slot' = slot ^ ((row>>2)&7))
// so the column-pattern b128 reads land 2-way (free) instead of 8-way.
__global__ __launch_bounds__(256, 2)
void attn_f32(const float* __restrict__ q_ws, const float* __restrict__ pk,
              const float* __restrict__ pv, float* __restrict__ a_pre)
{
    __shared__ float Qs[64][68];     // row-major, pre-scaled by 1/8
    __shared__ float Ps[64][68];
    __shared__ float Ks[64 * 64];    // swizzled
    __shared__ float Vs[64 * 64];    // swizzled

    const int t  = threadIdx.x;
    const int tx = t & 15, ty = t >> 4;
    const int qt = blockIdx.x & 31;
    const int bh = blockIdx.x >> 5;  // b*16 + h

    const float* qb = q_ws + ((size_t)bh * N_ + qt * 64) * HD_;
    const float* kb = pk + (size_t)bh * N_ * HD_;
    const float* vb = pv + (size_t)bh * N_ * HD_;

    {   // load Q tile, fold in 1/sqrt(hd) = 1/8
        const int r  = t >> 2;
        const int c0 = (t & 3) * 16;
        const float* src = qb + r * 64 + c0;
#pragma unroll
        for (int u = 0; u < 4; u++) {
            float4 v = *(const float4*)(src + 4 * u);
            v.x *= 0.125f; v.y *= 0.125f; v.z *= 0.125f; v.w *= 0.125f;
            *(float4*)&Qs[r][c0 + 4 * u] = v;
        }
    }

    float m_i[4], l_i[4], o[4][4];
#pragma unroll
    for (int i = 0; i < 4; i++) {
        m_i[i] = -1e30f; l_i[i] = 0.f;
#pragma unroll
        for (int j = 0; j < 4; j++) o[i][j] = 0.f;
    }

    for (int kt = 0; kt <= qt; kt++) {
        __syncthreads();   // prior PV reads of Ks/Vs/Ps done
        {   // stage K,V tile with slot swizzle
            const int r = t >> 2;
            const int x = (r >> 2) & 7;
            const float* ks = kb + (size_t)(kt * 64 + r) * 64 + (t & 3) * 16;
            const float* vs = vb + (size_t)(kt * 64 + r) * 64 + (t & 3) * 16;
#pragma unroll
            for (int u = 0; u < 4; u++) {
                const int q  = (t & 3) * 4 + u;
                const int qp = q ^ x;
                *(float4*)&Ks[r * 64 + qp * 4] = *(const float4*)(ks + 4 * u);
                *(float4*)&Vs[r * 64 + qp * 4] = *(const float4*)(vs + 4 * u);
            }
        }
        __syncthreads();

        float s[4][4];
#pragma unroll
        for (int i = 0; i < 4; i++)
#pragma unroll
            for (int j = 0; j < 4; j++) s[i][j] = 0.f;

#pragma unroll
        for (int d4 = 0; d4 < 16; d4++) {
            float4 q4[4], k4[4];
#pragma unroll
            for (int i = 0; i < 4; i++)
                q4[i] = *(const float4*)&Qs[ty * 4 + i][d4 * 4];
            const int slot = d4 ^ (tx & 7);   // (4tx+j)>>2 == tx
#pragma unroll
            for (int j = 0; j < 4; j++)
                k4[j] = *(const float4*)&Ks[(tx * 4 + j) * 64 + slot * 4];
#pragma unroll
            for (int i = 0; i < 4; i++)
#pragma unroll
                for (int j = 0; j < 4; j++)
                    s[i][j] += q4[i].x * k4[j].x + q4[i].y * k4[j].y
                             + q4[i].z * k4[j].z + q4[i].w * k4[j].w;
        }

        if (kt == qt) {   // diagonal tile causal mask (j>i masked)
#pragma unroll
            for (int i = 0; i < 4; i++)
#pragma unroll
                for (int j = 0; j < 4; j++)
                    if (tx * 4 + j > ty * 4 + i) s[i][j] = -1e30f;
        }

        // online softmax (rows split over the 16 tx lanes of each 16-lane group)
#pragma unroll
        for (int i = 0; i < 4; i++) {
            float rm = fmaxf(fmaxf(s[i][0], s[i][1]), fmaxf(s[i][2], s[i][3]));
            rm = fmaxf(rm, __shfl_xor(rm, 1, 16));
            rm = fmaxf(rm, __shfl_xor(rm, 2, 16));
            rm = fmaxf(rm, __shfl_xor(rm, 4, 16));
            rm = fmaxf(rm, __shfl_xor(rm, 8, 16));
            const float mnew = fmaxf(m_i[i], rm);
            const float corr = __expf(m_i[i] - mnew);
            const float p0 = __expf(s[i][0] - mnew);
            const float p1 = __expf(s[i][1] - mnew);
            const float p2 = __expf(s[i][2] - mnew);
            const float p3 = __expf(s[i][3] - mnew);
            float rs = p0 + p1 + p2 + p3;
            rs += __shfl_xor(rs, 1, 16);
            rs += __shfl_xor(rs, 2, 16);
            rs += __shfl_xor(rs, 4, 16);
            rs += __shfl_xor(rs, 8, 16);
            l_i[i] = l_i[i] * corr + rs;
            m_i[i] = mnew;
#pragma unroll
            for (int j = 0; j < 4; j++) o[i][j] *= corr;
            float4 pw; pw.x = p0; pw.y = p1; pw.z = p2; pw.w = p3;
            *(float4*)&Ps[ty * 4 + i][tx * 4] = pw;
        }
        __syncthreads();

        // O += P @ V
#pragma unroll
        for (int j4 = 0; j4 < 16; j4++) {
            float pr[4][4];
#pragma unroll
            for (int i = 0; i < 4; i++) {
                const float4 pv4 = *(const float4*)&Ps[ty * 4 + i][j4 * 4];
                pr[i][0] = pv4.x; pr[i][1] = pv4.y; pr[i][2] = pv4.z; pr[i][3] = pv4.w;
            }
            const int vslot = tx ^ (j4 & 7);   // (4j4+u)>>2 == j4
#pragma unroll
            for (int u = 0; u < 4; u++) {
                const float4 v4 = *(const float4*)&Vs[(j4 * 4 + u) * 64 + vslot * 4];
#pragma unroll
                for (int i = 0; i < 4; i++) {
                    o[i][0] = fmaf(pr[i][u], v4.x, o[i][0]);
                    o[i][1] = fmaf(pr[i][u], v4.y, o[i][1]);
                    o[i][2] = fmaf(pr[i][u], v4.z, o[i][2]);
                    o[i][3] = fmaf(pr[i][u], v4.w, o[i][3]);
                }
            }
        }
    }

    // final normalize + merge-heads write: a_pre[b, n, h*64 + d]
    const int b = bh >> 4, h = bh & 15;
#pragma unroll
    for (int i = 0; i < 4; i++) {
        const float inv = 1.0f / l_i[i];
        float4 v;
        v.x = o[i][0] * inv; v.y = o[i][1] * inv;
        v.z = o[i][2] * inv; v.w = o[i][3] * inv;
        const size_t row = (size_t)b * N_ + qt * 64 + ty * 4 + i;
        *(float4*)(a_pre + row * NX_ + h * 64 + tx * 4) = v;
    }
}

// ---------------------------------------------------------------------------
extern "C" void kernel_launch(void* const* d_in, const int* in_sizes, int n_in,
                              void* d_out, int out_size, void* d_ws, size_t ws_size,
                              hipStream_t stream)
{
    (void)in_sizes; (void)n_in; (void)out_size; (void)ws_size;
    const float* x    = (const float*)d_in[0];
    const float* wqkv = (const float*)d_in[1];
    const float* bqkv = (const float*)d_in[2];
    const float* wpr  = (const float*)d_in[3];
    const float* bpr  = (const float*)d_in[4];
    // d_in[5] (mask) ignored: causal mask applied analytically.

    float* out   = (float*)d_out;
    float* a_out = out;                                  // [B,N,NX]
    float* pk    = out + (size_t)M_ * NX_;               // present[0]: k [B,H,N,hd]
    float* pv    = pk + (size_t)B_ * NH_ * N_ * HD_;     // present[1]: v [B,H,N,hd]

    float* q_ws  = (float*)d_ws;                         // [B,H,N,hd]  (16 MB)
    float* a_pre = q_ws + (size_t)B_ * NH_ * N_ * HD_;   // [B,N,NX]    (16 MB)

    dim3 blk(256);
    gemm_f32<3 * NX_, 0><<<dim3((3 * NX_) / 128, M_ / 128), blk, 0, stream>>>(
        x, wqkv, bqkv, q_ws, pk, pv);
    attn_f32<<<dim3(B_ * NH_ * (N_ / 64)), blk, 0, stream>>>(q_ws, pk, pv, a_pre);
    gemm_f32<NX_, 1><<<dim3(NX_ / 128, M_ / 128), blk, 0, stream>>>(
        a_pre, wpr, bpr, a_out, nullptr, nullptr);
}

// Round 3
// 244.350 us; speedup vs baseline: 5.0475x; 5.0475x over previous
//
#include <hip/hip_runtime.h>
#include <cstddef>
#include <cstdint>

// Attention block (GPT-style) on MI355X, bf16-MFMA implementation.
//   x:[B,N,NX] f32, c_attn_w:[NX,3NX] f32, c_attn_b, c_proj_w:[NX,NX], c_proj_b
//   outputs: a:[B,N,NX] f32, present:[2,B,H,N,hd] f32  (k then v)
// mask input (d_in[5]) ignored: causal mask applied analytically.
#define NX_ 1024
#define NH_ 16
#define HD_ 64
#define B_  2
#define N_  2048
#define M_  (B_ * N_)   // 4096

typedef __attribute__((ext_vector_type(8))) short bf16x8;   // 8 bf16 (4 VGPR)
typedef __attribute__((ext_vector_type(4))) float f32x4;

// fp32 -> bf16 round-to-nearest-even
__device__ __forceinline__ unsigned short f2bf(float f) {
    union { float f; unsigned u; } v; v.f = f;
    return (unsigned short)((v.u + 0x7FFFu + ((v.u >> 16) & 1u)) >> 16);
}
__device__ __forceinline__ unsigned pk2bf(float a, float b) {
    return (unsigned)f2bf(a) | ((unsigned)f2bf(b) << 16);
}
// 2-bit row swizzle for 4-slot (64B) LDS rows
__device__ __forceinline__ int szf(int r) { return (r & 3) ^ ((r >> 2) & 3); }

// ---------------------------------------------------------------------------
// MFMA GEMM: out = A[M,1024] @ W[1024,NOUT] + bias.  BM=BN=128, BK=32,
// 256 thr / 4 waves (2x2), 64x64 per wave = 4x4 16x16 tiles.
// MODE 0 (qkv): A = fp32 x. Epilogue scatters:
//   sec0 q -> q_bf (bf16, pre-scaled by 0.125*log2e), sec1 k -> pk(f32)+k_bf,
//   sec2 v -> pv(f32)+v_t (bf16 TRANSPOSED [bh][d][n]).
// MODE 1 (proj): A = bf16 a_pre, plain fp32 out.
template<int NOUT, int MODE>
__global__ __launch_bounds__(256, 2)
void gemm_mfma(const float* __restrict__ Af, const unsigned short* __restrict__ Ah,
               const float* __restrict__ W, const float* __restrict__ bias,
               float* __restrict__ o_pk, float* __restrict__ o_pv,
               unsigned short* __restrict__ o_q, unsigned short* __restrict__ o_k,
               unsigned short* __restrict__ o_vt, float* __restrict__ o_f)
{
    __shared__ __align__(16) unsigned short As[2][128 * 32];
    __shared__ __align__(16) unsigned short Bs[2][128 * 32];
    const int t = threadIdx.x;
    const int l = t & 63;
    const int g = l >> 4, q15 = l & 15;
    const int w = t >> 6, wm = w >> 1, wn = w & 1;
    const int m0 = blockIdx.y * 128, j0 = blockIdx.x * 128;

    f32x4 acc[4][4];
#pragma unroll
    for (int i = 0; i < 4; i++)
#pragma unroll
        for (int j = 0; j < 4; j++) { acc[i][j][0]=0.f; acc[i][j][1]=0.f; acc[i][j][2]=0.f; acc[i][j][3]=0.f; }

    const int ra = t >> 1, ca = (t & 1) * 16;     // A staging: row 0..127, col 0/16
    const int nb = t & 127, kb0 = (t >> 7) * 16;  // B staging: col 0..127, k 0/16

    unsigned sa[8], sb[8];                        // staged 16 bf16 each

#define LOAD_A(K0)                                                              \
    do {                                                                        \
        if (MODE == 0) {                                                        \
            const float* ap = Af + (size_t)(m0 + ra) * 1024 + (K0) + ca;        \
            float4 x0 = *(const float4*)(ap);                                   \
            float4 x1 = *(const float4*)(ap + 4);                               \
            float4 x2 = *(const float4*)(ap + 8);                               \
            float4 x3 = *(const float4*)(ap + 12);                              \
            sa[0] = pk2bf(x0.x, x0.y); sa[1] = pk2bf(x0.z, x0.w);               \
            sa[2] = pk2bf(x1.x, x1.y); sa[3] = pk2bf(x1.z, x1.w);               \
            sa[4] = pk2bf(x2.x, x2.y); sa[5] = pk2bf(x2.z, x2.w);               \
            sa[6] = pk2bf(x3.x, x3.y); sa[7] = pk2bf(x3.z, x3.w);               \
        } else {                                                                \
            const uint4* ap = (const uint4*)(Ah + (size_t)(m0 + ra) * 1024 + (K0) + ca); \
            uint4 u0 = ap[0], u1 = ap[1];                                       \
            sa[0]=u0.x; sa[1]=u0.y; sa[2]=u0.z; sa[3]=u0.w;                     \
            sa[4]=u1.x; sa[5]=u1.y; sa[6]=u1.z; sa[7]=u1.w;                     \
        }                                                                       \
    } while (0)

#define LOAD_B(K0)                                                              \
    do {                                                                        \
        const float* wp = W + (size_t)((K0) + kb0) * NOUT + j0 + nb;            \
        float v0,v1;                                                            \
        _Pragma("unroll")                                                       \
        for (int i = 0; i < 8; i++) {                                           \
            v0 = wp[(size_t)(2*i) * NOUT]; v1 = wp[(size_t)(2*i+1) * NOUT];     \
            sb[i] = pk2bf(v0, v1);                                              \
        }                                                                       \
    } while (0)

#define COMMIT_AB(BUF)                                                          \
    do {                                                                        \
        unsigned short* da = &As[BUF][ra * 32];                                 \
        const int s0a = (ca >> 3);                                              \
        *(uint4*)&da[((s0a ^ szf(ra)) & 3) * 8]       = *(uint4*)&sa[0];        \
        *(uint4*)&da[(((s0a + 1) ^ szf(ra)) & 3) * 8] = *(uint4*)&sa[4];        \
        unsigned short* db = &Bs[BUF][nb * 32];                                 \
        const int s0b = (kb0 >> 3);                                             \
        *(uint4*)&db[((s0b ^ szf(nb)) & 3) * 8]       = *(uint4*)&sb[0];        \
        *(uint4*)&db[(((s0b + 1) ^ szf(nb)) & 3) * 8] = *(uint4*)&sb[4];        \
    } while (0)

    LOAD_A(0); LOAD_B(0); COMMIT_AB(0);
    __syncthreads();

    for (int k0 = 0; k0 < 1024; k0 += 32) {
        const int buf = (k0 >> 5) & 1;
        const bool more = (k0 + 32 < 1024);
        if (more) { LOAD_A(k0 + 32); LOAD_B(k0 + 32); }   // issue early (T14)

        bf16x8 af[4], bf[4];
#pragma unroll
        for (int mt = 0; mt < 4; mt++) {
            const int m = wm * 64 + mt * 16 + q15;
            af[mt] = *(const bf16x8*)&As[buf][m * 32 + ((g ^ szf(m)) & 3) * 8];
        }
#pragma unroll
        for (int nt = 0; nt < 4; nt++) {
            const int n = wn * 64 + nt * 16 + q15;
            bf[nt] = *(const bf16x8*)&Bs[buf][n * 32 + ((g ^ szf(n)) & 3) * 8];
        }
#pragma unroll
        for (int mt = 0; mt < 4; mt++)
#pragma unroll
            for (int nt = 0; nt < 4; nt++)
                acc[mt][nt] = __builtin_amdgcn_mfma_f32_16x16x32_bf16(af[mt], bf[nt], acc[mt][nt], 0, 0, 0);

        if (more) COMMIT_AB(buf ^ 1);                      // write late
        __syncthreads();
    }

    // epilogue
#pragma unroll
    for (int nt = 0; nt < 4; nt++) {
        const int ncol = wn * 64 + nt * 16 + q15;
        const int jc = j0 + ncol;
        const float bz = bias[jc];
        const int sec = jc >> 10, jl = jc & 1023, hh = jl >> 6, dd = jl & 63;
#pragma unroll
        for (int mt = 0; mt < 4; mt++) {
#pragma unroll
            for (int r = 0; r < 4; r++) {
                const int m = m0 + wm * 64 + mt * 16 + g * 4 + r;
                const float val = acc[mt][nt][r] + bz;
                if (MODE == 1) {
                    o_f[(size_t)m * NOUT + jc] = val;
                } else {
                    const int bb = m >> 11, nn = m & 2047;
                    const int bhh = bb * NH_ + hh;
                    const size_t idx = ((size_t)bhh * N_ + nn) * HD_ + dd;
                    if (sec == 0)      o_q[idx] = f2bf(val * 0.18033688f); // 1/8 * log2(e)
                    else if (sec == 1) { o_pk[idx] = val; o_k[idx] = f2bf(val); }
                    else               { o_pv[idx] = val;
                                         o_vt[((size_t)bhh * HD_ + dd) * N_ + nn] = f2bf(val); }
                }
            }
        }
    }
#undef LOAD_A
#undef LOAD_B
#undef COMMIT_AB
}

// ---------------------------------------------------------------------------
// Flash attention, bf16 MFMA. Block = (bh, 64-row q-tile), 4 waves x 16 rows.
// Swapped QK^T: S^T = mfma(K, Q) -> lane-local softmax (col q = lane&15).
// PV as O^T = mfma(V^T, P): rescale stays lane-local. P routed via per-wave LDS.
// K rows and V^T rows staged double-buffered with 8-slot XOR swizzle.
__global__ __launch_bounds__(256, 4)
void attn_mfma(const unsigned short* __restrict__ q_bf,
               const unsigned short* __restrict__ k_bf,
               const unsigned short* __restrict__ v_t,
               unsigned short* __restrict__ a_pre)
{
    __shared__ __align__(16) unsigned short Ks[2][64 * 64];
    __shared__ __align__(16) unsigned short Vt[2][64 * 64];
    __shared__ __align__(16) unsigned short Ps[64 * 64];

    const int t = threadIdx.x, l = t & 63, w = t >> 6;
    const int g = l >> 4, q15 = l & 15;
    const int bh = (int)blockIdx.x & 31;
    const int qt = 31 - ((int)blockIdx.x >> 5);   // LPT: heaviest q-tiles first
    const int b = bh >> 4, h = bh & 15;

    const unsigned short* kb  = k_bf + (size_t)bh * N_ * HD_;
    const unsigned short* vtb = v_t  + (size_t)bh * HD_ * N_;

    // Q fragments (B operand): col = q15, k = d = g*8 + j (+32 per kstep)
    const int qrow = w * 16 + q15;                // q row within 64-tile
    const unsigned short* qp = q_bf + ((size_t)bh * N_ + (size_t)qt * 64 + qrow) * HD_ + g * 8;
    const bf16x8 qf0 = *(const bf16x8*)(qp);
    const bf16x8 qf1 = *(const bf16x8*)(qp + 32);

    // staging: thread t -> row sr (K row kc / V^T row d), 2 slots of 8 bf16
    const int sr = t >> 2, sc2 = (t & 3) * 2;
    uint4 stgK0, stgK1, stgV0, stgV1;

#define ISSUE(KT)                                                               \
    do {                                                                        \
        const uint4* ksrc = (const uint4*)(kb + ((size_t)((KT) * 64 + sr)) * HD_ + sc2 * 8); \
        stgK0 = ksrc[0]; stgK1 = ksrc[1];                                       \
        const uint4* vsrc = (const uint4*)(vtb + (size_t)sr * N_ + (KT) * 64 + sc2 * 8);     \
        stgV0 = vsrc[0]; stgV1 = vsrc[1];                                       \
    } while (0)

#define COMMIT(BUF)                                                             \
    do {                                                                        \
        unsigned short* kd = &Ks[BUF][sr * 64];                                 \
        *(uint4*)&kd[((sc2 ^ (sr & 7)) & 7) * 8]       = stgK0;                 \
        *(uint4*)&kd[(((sc2 + 1) ^ (sr & 7)) & 7) * 8] = stgK1;                 \
        unsigned short* vd = &Vt[BUF][sr * 64];                                 \
        *(uint4*)&vd[((sc2 ^ (sr & 7)) & 7) * 8]       = stgV0;                 \
        *(uint4*)&vd[(((sc2 + 1) ^ (sr & 7)) & 7) * 8] = stgV1;                 \
    } while (0)

    ISSUE(0); COMMIT(0);
    __syncthreads();

    float m_i = -3.0e38f, l_i = 0.f;
    f32x4 oacc[4];
#pragma unroll
    for (int i = 0; i < 4; i++) { oacc[i][0]=0.f; oacc[i][1]=0.f; oacc[i][2]=0.f; oacc[i][3]=0.f; }

    int cur = 0;
    char* const prow = (char*)Ps + qrow * 128;
    const int psw = (qrow & 7) << 4;

    for (int kt = 0; kt <= qt; kt++) {
        const bool more = (kt < qt);
        if (more) ISSUE(kt + 1);                  // issue next tile early

        // ---- S^T = K . Q^T  (rows kc, cols q)
        f32x4 sacc[4];
#pragma unroll
        for (int i = 0; i < 4; i++) { sacc[i][0]=0.f; sacc[i][1]=0.f; sacc[i][2]=0.f; sacc[i][3]=0.f; }
#pragma unroll
        for (int kt4 = 0; kt4 < 4; kt4++) {
            const int row = kt4 * 16 + q15;
            const bf16x8 kf0 = *(const bf16x8*)&Ks[cur][row * 64 + ((g ^ (row & 7)) & 7) * 8];
            sacc[kt4] = __builtin_amdgcn_mfma_f32_16x16x32_bf16(kf0, qf0, sacc[kt4], 0, 0, 0);
            const bf16x8 kf1 = *(const bf16x8*)&Ks[cur][row * 64 + (((g + 4) ^ (row & 7)) & 7) * 8];
            sacc[kt4] = __builtin_amdgcn_mfma_f32_16x16x32_bf16(kf1, qf1, sacc[kt4], 0, 0, 0);
        }

        float sv[16];
#pragma unroll
        for (int kt4 = 0; kt4 < 4; kt4++)
#pragma unroll
            for (int r = 0; r < 4; r++) sv[kt4 * 4 + r] = sacc[kt4][r];

        if (kt == qt) {   // causal mask on diagonal tile: kc_local > q_local
#pragma unroll
            for (int kt4 = 0; kt4 < 4; kt4++)
#pragma unroll
                for (int r = 0; r < 4; r++)
                    if (kt4 * 16 + g * 4 + r > qrow) sv[kt4 * 4 + r] = -3.0e38f;
        }

        // ---- online softmax (log2 domain; scale folded into q_bf)
        float mx = sv[0];
#pragma unroll
        for (int i = 1; i < 16; i++) mx = fmaxf(mx, sv[i]);
        mx = fmaxf(mx, __shfl_xor(mx, 16));
        mx = fmaxf(mx, __shfl_xor(mx, 32));
        const float mnew = fmaxf(m_i, mx);
        const float corr = exp2f(m_i - mnew);
        float ps = 0.f;
#pragma unroll
        for (int i = 0; i < 16; i++) { const float p = exp2f(sv[i] - mnew); sv[i] = p; ps += p; }
        ps += __shfl_xor(ps, 16);
        ps += __shfl_xor(ps, 32);
        l_i = l_i * corr + ps;
        m_i = mnew;
#pragma unroll
        for (int dt = 0; dt < 4; dt++) {
            oacc[dt][0] *= corr; oacc[dt][1] *= corr; oacc[dt][2] *= corr; oacc[dt][3] *= corr;
        }

        // ---- write P (bf16) into this wave's private Ps rows
#pragma unroll
        for (int kt4 = 0; kt4 < 4; kt4++) {
#pragma unroll
            for (int j2 = 0; j2 < 2; j2++) {
                const int kc = kt4 * 16 + g * 4 + j2 * 2;
                *(unsigned*)(prow + ((kc * 2) ^ psw)) = pk2bf(sv[kt4 * 4 + j2 * 2], sv[kt4 * 4 + j2 * 2 + 1]);
            }
        }

        // ---- O^T += V^T . P   (rows d, cols q)
        {
            const bf16x8 pf0 = *(const bf16x8*)(prow + ((g * 16) ^ psw));
#pragma unroll
            for (int dt = 0; dt < 4; dt++) {
                const int vrow = dt * 16 + q15;
                const bf16x8 vf = *(const bf16x8*)&Vt[cur][vrow * 64 + ((g ^ (vrow & 7)) & 7) * 8];
                oacc[dt] = __builtin_amdgcn_mfma_f32_16x16x32_bf16(vf, pf0, oacc[dt], 0, 0, 0);
            }
            const bf16x8 pf1 = *(const bf16x8*)(prow + (((g + 4) * 16) ^ psw));
#pragma unroll
            for (int dt = 0; dt < 4; dt++) {
                const int vrow = dt * 16 + q15;
                const bf16x8 vf = *(const bf16x8*)&Vt[cur][vrow * 64 + (((g + 4) ^ (vrow & 7)) & 7) * 8];
                oacc[dt] = __builtin_amdgcn_mfma_f32_16x16x32_bf16(vf, pf1, oacc[dt], 0, 0, 0);
            }
        }

        if (more) COMMIT(cur ^ 1);                // write next tile late
        __syncthreads();
        cur ^= 1;
    }

    // ---- output: a_pre[b*N + qt*64 + qrow][h*64 + d], bf16
    const float inv = 1.0f / l_i;
    unsigned short* ap2 = a_pre + ((size_t)(b * N_ + qt * 64 + qrow)) * NX_ + h * 64;
#pragma unroll
    for (int dt = 0; dt < 4; dt++) {
#pragma unroll
        for (int j2 = 0; j2 < 2; j2++) {
            const int d = dt * 16 + g * 4 + j2 * 2;
            *(unsigned*)(ap2 + d) = pk2bf(oacc[dt][j2 * 2] * inv, oacc[dt][j2 * 2 + 1] * inv);
        }
    }
#undef ISSUE
#undef COMMIT
}

// ---------------------------------------------------------------------------
extern "C" void kernel_launch(void* const* d_in, const int* in_sizes, int n_in,
                              void* d_out, int out_size, void* d_ws, size_t ws_size,
                              hipStream_t stream)
{
    (void)in_sizes; (void)n_in; (void)out_size; (void)ws_size;
    const float* x    = (const float*)d_in[0];
    const float* wqkv = (const float*)d_in[1];
    const float* bqkv = (const float*)d_in[2];
    const float* wpr  = (const float*)d_in[3];
    const float* bpr  = (const float*)d_in[4];
    // d_in[5] (mask) ignored: causal mask applied analytically.

    float* out   = (float*)d_out;
    float* a_out = out;                                  // [B,N,NX] f32
    float* pk    = out + (size_t)M_ * NX_;               // present[0]: k [B,H,N,hd]
    float* pv    = pk + (size_t)B_ * NH_ * N_ * HD_;     // present[1]: v

    // workspace (32 MB total): bf16 q/k/v^T + bf16 attention output
    unsigned short* q_bf  = (unsigned short*)d_ws;                       // [bh][n][d]
    unsigned short* k_bf  = q_bf + (size_t)B_ * NH_ * N_ * HD_;          // [bh][n][d]
    unsigned short* v_t   = k_bf + (size_t)B_ * NH_ * N_ * HD_;          // [bh][d][n]
    unsigned short* a_pre = v_t  + (size_t)B_ * NH_ * N_ * HD_;          // [m][1024]

    gemm_mfma<3 * NX_, 0><<<dim3(24, 32), 256, 0, stream>>>(
        x, nullptr, wqkv, bqkv, pk, pv, q_bf, k_bf, v_t, nullptr);
    attn_mfma<<<dim3(32 * 32), 256, 0, stream>>>(q_bf, k_bf, v_t, a_pre);
    gemm_mfma<NX_, 1><<<dim3(8, 32), 256, 0, stream>>>(
        nullptr, a_pre, wpr, bpr, nullptr, nullptr, nullptr, nullptr, nullptr, a_out);
}

// Round 4
// 218.033 us; speedup vs baseline: 5.6568x; 1.1207x over previous
//
#include <hip/hip_runtime.h>
#include <cstddef>
#include <cstdint>

// GPT-style attention block on MI355X (gfx950), bf16-MFMA.
//   x:[B,N,NX] f32, c_attn_w:[NX,3NX] f32, c_attn_b, c_proj_w:[NX,NX], c_proj_b
//   outputs: a:[B,N,NX] f32, present:[2,B,H,N,hd] f32  (k then v)
// mask input (d_in[5]) ignored: causal mask applied analytically.
#define NX_ 1024
#define NH_ 16
#define HD_ 64
#define B_  2
#define N_  2048
#define M_  (B_ * N_)   // 4096

typedef __attribute__((ext_vector_type(8))) short bf16x8;   // 8 bf16 (4 VGPR)
typedef __attribute__((ext_vector_type(4))) float f32x4;

// fp32 -> bf16 round-to-nearest-even
__device__ __forceinline__ unsigned short f2bf(float f) {
    union { float f; unsigned u; } v; v.f = f;
    return (unsigned short)((v.u + 0x7FFFu + ((v.u >> 16) & 1u)) >> 16);
}
__device__ __forceinline__ unsigned pk2bf(float a, float b) {
    return (unsigned)f2bf(a) | ((unsigned)f2bf(b) << 16);
}

// async global->LDS, 16B per lane; LDS dest = wave-uniform base + lane*16
__device__ __forceinline__ void gload_lds16(const void* g, void* l) {
    __builtin_amdgcn_global_load_lds(
        (const __attribute__((address_space(1))) unsigned int*)g,
        (__attribute__((address_space(3))) unsigned int*)l, 16, 0, 0);
}

// ---------------------------------------------------------------------------
// Pre-pass 1: x f32 -> bf16 (straight layout), 8 elems/thread
__global__ void conv_x(const float* __restrict__ in, unsigned short* __restrict__ outb)
{
    const size_t i = ((size_t)blockIdx.x * 256 + threadIdx.x) * 8;
    const float4 a = *(const float4*)(in + i);
    const float4 b = *(const float4*)(in + i + 4);
    uint4 o;
    o.x = pk2bf(a.x, a.y); o.y = pk2bf(a.z, a.w);
    o.z = pk2bf(b.x, b.y); o.w = pk2bf(b.z, b.w);
    *(uint4*)(outb + i) = o;
}

// Pre-pass 2: W[1024][ncols] f32 -> Wt[ncols][1024] bf16 (transpose via LDS tile)
__global__ void conv_t(const float* __restrict__ W, unsigned short* __restrict__ Wt, int ncols)
{
    __shared__ unsigned short tile[32][40];
    const int t = threadIdx.x;
    const int n0 = blockIdx.x * 32, k0 = blockIdx.y * 32;
    const int r = t >> 3, c4 = (t & 7) * 4;
    const float4 v = *(const float4*)(W + (size_t)(k0 + r) * ncols + n0 + c4);
    tile[r][c4 + 0] = f2bf(v.x); tile[r][c4 + 1] = f2bf(v.y);
    tile[r][c4 + 2] = f2bf(v.z); tile[r][c4 + 3] = f2bf(v.w);
    __syncthreads();
    uint2 o;
    o.x = (unsigned)tile[c4 + 0][r] | ((unsigned)tile[c4 + 1][r] << 16);
    o.y = (unsigned)tile[c4 + 2][r] | ((unsigned)tile[c4 + 3][r] << 16);
    *(uint2*)(Wt + (size_t)(n0 + r) * 1024 + k0 + c4) = o;
}

// ---------------------------------------------------------------------------
// m97-style bf16 GEMM: out = A[M,1024](bf16) @ Wt[NOUT,1024]^T(bf16) + bias.
// BM=BN=128, BK=32, 4 waves (2x2), 64x64/wave = 4x4 MFMA tiles, dbuf LDS,
// global_load_lds staging with pre-swizzled global source (2-bit slot XOR).
// MODE 0 (qkv): scatter epilogue -> q_bf (scaled), pk+k_bf, pv+v_t(transposed).
// MODE 1 (proj): plain f32 out.
template<int NOUT, int MODE>
__global__ __launch_bounds__(256, 3)
void gemm_mfma(const unsigned short* __restrict__ Ab, const unsigned short* __restrict__ Wt,
               const float* __restrict__ bias,
               float* __restrict__ o_pk, float* __restrict__ o_pv,
               unsigned short* __restrict__ o_q, unsigned short* __restrict__ o_k,
               unsigned short* __restrict__ o_vt, float* __restrict__ o_f)
{
    __shared__ __align__(16) unsigned short As[2][128 * 32];
    __shared__ __align__(16) unsigned short Bs[2][128 * 32];
    const int t = threadIdx.x, l = t & 63;
    const int g = l >> 4, q15 = l & 15;
    const int w = t >> 6, wm = w >> 1, wn = w & 1;
    const int m0 = blockIdx.y * 128, j0 = blockIdx.x * 128;

    f32x4 acc[4][4];
#pragma unroll
    for (int i = 0; i < 4; i++)
#pragma unroll
        for (int j = 0; j < 4; j++) { acc[i][j][0]=0.f; acc[i][j][1]=0.f; acc[i][j][2]=0.f; acc[i][j][3]=0.f; }

    // staging geometry: chunk = (w*2+i)*64 + l covers LDS bytes chunk*16;
    // row = chunk>>2, lds slot = chunk&3; global slot = lds_slot ^ (row&3)
    const int srow[2] = { (w * 2 + 0) * 16 + (l >> 2), (w * 2 + 1) * 16 + (l >> 2) };
    const int kct0 = (l & 3) ^ (srow[0] & 3);
    const int kct1 = (l & 3) ^ (srow[1] & 3);

#define STAGE(BUF, K0)                                                          \
    do {                                                                        \
        gload_lds16(Ab + (size_t)(m0 + srow[0]) * 1024 + (K0) + kct0 * 8,       \
                    &As[BUF][(w * 2 + 0) * 64 * 8]);                            \
        gload_lds16(Ab + (size_t)(m0 + srow[1]) * 1024 + (K0) + kct1 * 8,       \
                    &As[BUF][(w * 2 + 1) * 64 * 8]);                            \
        gload_lds16(Wt + (size_t)(j0 + srow[0]) * 1024 + (K0) + kct0 * 8,       \
                    &Bs[BUF][(w * 2 + 0) * 64 * 8]);                            \
        gload_lds16(Wt + (size_t)(j0 + srow[1]) * 1024 + (K0) + kct1 * 8,       \
                    &Bs[BUF][(w * 2 + 1) * 64 * 8]);                            \
    } while (0)

    STAGE(0, 0);
    __syncthreads();

    for (int k0 = 0; k0 < 1024; k0 += 32) {
        const int buf = (k0 >> 5) & 1;
        if (k0 + 32 < 1024) STAGE(buf ^ 1, k0 + 32);   // prefetch next K-slab

        bf16x8 af[4], bf[4];
#pragma unroll
        for (int mt = 0; mt < 4; mt++) {
            const int m = wm * 64 + mt * 16 + q15;
            af[mt] = *(const bf16x8*)&As[buf][m * 32 + ((g ^ (m & 3)) & 3) * 8];
        }
#pragma unroll
        for (int nt = 0; nt < 4; nt++) {
            const int n = wn * 64 + nt * 16 + q15;
            bf[nt] = *(const bf16x8*)&Bs[buf][n * 32 + ((g ^ (n & 3)) & 3) * 8];
        }
#pragma unroll
        for (int mt = 0; mt < 4; mt++)
#pragma unroll
            for (int nt = 0; nt < 4; nt++)
                acc[mt][nt] = __builtin_amdgcn_mfma_f32_16x16x32_bf16(af[mt], bf[nt], acc[mt][nt], 0, 0, 0);

        __syncthreads();   // drains gload_lds (vmcnt) + guards buf reuse
    }

    // epilogue
#pragma unroll
    for (int nt = 0; nt < 4; nt++) {
        const int ncol = wn * 64 + nt * 16 + q15;
        const int jc = j0 + ncol;
        const float bz = bias[jc];
        const int sec = jc >> 10, jl = jc & 1023, hh = jl >> 6, dd = jl & 63;
#pragma unroll
        for (int mt = 0; mt < 4; mt++) {
#pragma unroll
            for (int r = 0; r < 4; r++) {
                const int m = m0 + wm * 64 + mt * 16 + g * 4 + r;
                const float val = acc[mt][nt][r] + bz;
                if (MODE == 1) {
                    o_f[(size_t)m * NOUT + jc] = val;
                } else {
                    const int bb = m >> 11, nn = m & 2047;
                    const int bhh = bb * NH_ + hh;
                    const size_t idx = ((size_t)bhh * N_ + nn) * HD_ + dd;
                    if (sec == 0)      o_q[idx] = f2bf(val * 0.18033688f); // 1/8 * log2(e)
                    else if (sec == 1) { o_pk[idx] = val; o_k[idx] = f2bf(val); }
                    else               { o_pv[idx] = val;
                                         o_vt[((size_t)bhh * HD_ + dd) * N_ + nn] = f2bf(val); }
                }
            }
        }
    }
#undef STAGE
}

// ---------------------------------------------------------------------------
// Flash attention, bf16 MFMA (unchanged from round 3 — verified).
// Block = (bh, 64-row q-tile), 4 waves x 16 rows. Swapped QK^T: S^T = mfma(K,Q)
// -> lane-local softmax. PV as O^T = mfma(V^T, P). Double-buffered K/V^T with
// 8-slot XOR swizzle; P routed via per-wave LDS rows.
__global__ __launch_bounds__(256, 4)
void attn_mfma(const unsigned short* __restrict__ q_bf,
               const unsigned short* __restrict__ k_bf,
               const unsigned short* __restrict__ v_t,
               unsigned short* __restrict__ a_pre)
{
    __shared__ __align__(16) unsigned short Ks[2][64 * 64];
    __shared__ __align__(16) unsigned short Vt[2][64 * 64];
    __shared__ __align__(16) unsigned short Ps[64 * 64];

    const int t = threadIdx.x, l = t & 63, w = t >> 6;
    const int g = l >> 4, q15 = l & 15;
    const int bh = (int)blockIdx.x & 31;
    const int qt = 31 - ((int)blockIdx.x >> 5);   // LPT: heaviest q-tiles first
    const int b = bh >> 4, h = bh & 15;

    const unsigned short* kb  = k_bf + (size_t)bh * N_ * HD_;
    const unsigned short* vtb = v_t  + (size_t)bh * HD_ * N_;

    const int qrow = w * 16 + q15;
    const unsigned short* qp = q_bf + ((size_t)bh * N_ + (size_t)qt * 64 + qrow) * HD_ + g * 8;
    const bf16x8 qf0 = *(const bf16x8*)(qp);
    const bf16x8 qf1 = *(const bf16x8*)(qp + 32);

    const int sr = t >> 2, sc2 = (t & 3) * 2;
    uint4 stgK0, stgK1, stgV0, stgV1;

#define ISSUE(KT)                                                               \
    do {                                                                        \
        const uint4* ksrc = (const uint4*)(kb + ((size_t)((KT) * 64 + sr)) * HD_ + sc2 * 8); \
        stgK0 = ksrc[0]; stgK1 = ksrc[1];                                       \
        const uint4* vsrc = (const uint4*)(vtb + (size_t)sr * N_ + (KT) * 64 + sc2 * 8);     \
        stgV0 = vsrc[0]; stgV1 = vsrc[1];                                       \
    } while (0)

#define COMMIT(BUF)                                                             \
    do {                                                                        \
        unsigned short* kd = &Ks[BUF][sr * 64];                                 \
        *(uint4*)&kd[((sc2 ^ (sr & 7)) & 7) * 8]       = stgK0;                 \
        *(uint4*)&kd[(((sc2 + 1) ^ (sr & 7)) & 7) * 8] = stgK1;                 \
        unsigned short* vd = &Vt[BUF][sr * 64];                                 \
        *(uint4*)&vd[((sc2 ^ (sr & 7)) & 7) * 8]       = stgV0;                 \
        *(uint4*)&vd[(((sc2 + 1) ^ (sr & 7)) & 7) * 8] = stgV1;                 \
    } while (0)

    ISSUE(0); COMMIT(0);
    __syncthreads();

    float m_i = -3.0e38f, l_i = 0.f;
    f32x4 oacc[4];
#pragma unroll
    for (int i = 0; i < 4; i++) { oacc[i][0]=0.f; oacc[i][1]=0.f; oacc[i][2]=0.f; oacc[i][3]=0.f; }

    int cur = 0;
    char* const prow = (char*)Ps + qrow * 128;
    const int psw = (qrow & 7) << 4;

    for (int kt = 0; kt <= qt; kt++) {
        const bool more = (kt < qt);
        if (more) ISSUE(kt + 1);

        f32x4 sacc[4];
#pragma unroll
        for (int i = 0; i < 4; i++) { sacc[i][0]=0.f; sacc[i][1]=0.f; sacc[i][2]=0.f; sacc[i][3]=0.f; }
#pragma unroll
        for (int kt4 = 0; kt4 < 4; kt4++) {
            const int row = kt4 * 16 + q15;
            const bf16x8 kf0 = *(const bf16x8*)&Ks[cur][row * 64 + ((g ^ (row & 7)) & 7) * 8];
            sacc[kt4] = __builtin_amdgcn_mfma_f32_16x16x32_bf16(kf0, qf0, sacc[kt4], 0, 0, 0);
            const bf16x8 kf1 = *(const bf16x8*)&Ks[cur][row * 64 + (((g + 4) ^ (row & 7)) & 7) * 8];
            sacc[kt4] = __builtin_amdgcn_mfma_f32_16x16x32_bf16(kf1, qf1, sacc[kt4], 0, 0, 0);
        }

        float sv[16];
#pragma unroll
        for (int kt4 = 0; kt4 < 4; kt4++)
#pragma unroll
            for (int r = 0; r < 4; r++) sv[kt4 * 4 + r] = sacc[kt4][r];

        if (kt == qt) {
#pragma unroll
            for (int kt4 = 0; kt4 < 4; kt4++)
#pragma unroll
                for (int r = 0; r < 4; r++)
                    if (kt4 * 16 + g * 4 + r > qrow) sv[kt4 * 4 + r] = -3.0e38f;
        }

        float mx = sv[0];
#pragma unroll
        for (int i = 1; i < 16; i++) mx = fmaxf(mx, sv[i]);
        mx = fmaxf(mx, __shfl_xor(mx, 16));
        mx = fmaxf(mx, __shfl_xor(mx, 32));
        const float mnew = fmaxf(m_i, mx);
        const float corr = exp2f(m_i - mnew);
        float ps = 0.f;
#pragma unroll
        for (int i = 0; i < 16; i++) { const float p = exp2f(sv[i] - mnew); sv[i] = p; ps += p; }
        ps += __shfl_xor(ps, 16);
        ps += __shfl_xor(ps, 32);
        l_i = l_i * corr + ps;
        m_i = mnew;
#pragma unroll
        for (int dt = 0; dt < 4; dt++) {
            oacc[dt][0] *= corr; oacc[dt][1] *= corr; oacc[dt][2] *= corr; oacc[dt][3] *= corr;
        }

#pragma unroll
        for (int kt4 = 0; kt4 < 4; kt4++) {
#pragma unroll
            for (int j2 = 0; j2 < 2; j2++) {
                const int kc = kt4 * 16 + g * 4 + j2 * 2;
                *(unsigned*)(prow + ((kc * 2) ^ psw)) = pk2bf(sv[kt4 * 4 + j2 * 2], sv[kt4 * 4 + j2 * 2 + 1]);
            }
        }

        {
            const bf16x8 pf0 = *(const bf16x8*)(prow + ((g * 16) ^ psw));
#pragma unroll
            for (int dt = 0; dt < 4; dt++) {
                const int vrow = dt * 16 + q15;
                const bf16x8 vf = *(const bf16x8*)&Vt[cur][vrow * 64 + ((g ^ (vrow & 7)) & 7) * 8];
                oacc[dt] = __builtin_amdgcn_mfma_f32_16x16x32_bf16(vf, pf0, oacc[dt], 0, 0, 0);
            }
            const bf16x8 pf1 = *(const bf16x8*)(prow + (((g + 4) * 16) ^ psw));
#pragma unroll
            for (int dt = 0; dt < 4; dt++) {
                const int vrow = dt * 16 + q15;
                const bf16x8 vf = *(const bf16x8*)&Vt[cur][vrow * 64 + (((g + 4) ^ (vrow & 7)) & 7) * 8];
                oacc[dt] = __builtin_amdgcn_mfma_f32_16x16x32_bf16(vf, pf1, oacc[dt], 0, 0, 0);
            }
        }

        if (more) COMMIT(cur ^ 1);
        __syncthreads();
        cur ^= 1;
    }

    const float inv = 1.0f / l_i;
    unsigned short* ap2 = a_pre + ((size_t)(b * N_ + qt * 64 + qrow)) * NX_ + h * 64;
#pragma unroll
    for (int dt = 0; dt < 4; dt++) {
#pragma unroll
        for (int j2 = 0; j2 < 2; j2++) {
            const int d = dt * 16 + g * 4 + j2 * 2;
            *(unsigned*)(ap2 + d) = pk2bf(oacc[dt][j2 * 2] * inv, oacc[dt][j2 * 2 + 1] * inv);
        }
    }
#undef ISSUE
#undef COMMIT
}

// ---------------------------------------------------------------------------
extern "C" void kernel_launch(void* const* d_in, const int* in_sizes, int n_in,
                              void* d_out, int out_size, void* d_ws, size_t ws_size,
                              hipStream_t stream)
{
    (void)in_sizes; (void)n_in; (void)out_size; (void)ws_size;
    const float* x    = (const float*)d_in[0];
    const float* wqkv = (const float*)d_in[1];
    const float* bqkv = (const float*)d_in[2];
    const float* wpr  = (const float*)d_in[3];
    const float* bpr  = (const float*)d_in[4];
    // d_in[5] (mask) ignored: causal mask applied analytically.

    float* out   = (float*)d_out;
    float* a_out = out;                                  // [B,N,NX] f32
    float* pk    = out + (size_t)M_ * NX_;               // present[0]: k [B,H,N,hd]
    float* pv    = pk + (size_t)B_ * NH_ * N_ * HD_;     // present[1]: v

    // workspace (40 MB): bf16 x / q / k / v^T / transposed weights.
    // a_pre aliases xb: xb is fully consumed by the qkv GEMM before attn writes.
    const size_t SEG = (size_t)M_ * NX_;                 // 4M elems
    unsigned short* xb      = (unsigned short*)d_ws;     // [4096][1024]
    unsigned short* q_bf    = xb + SEG;                  // [bh][n][d]
    unsigned short* k_bf    = q_bf + SEG;                // [bh][n][d]
    unsigned short* v_t     = k_bf + SEG;                // [bh][d][n]
    unsigned short* wqkv_t  = v_t + SEG;                 // [3072][1024]
    unsigned short* wproj_t = wqkv_t + (size_t)3 * NX_ * NX_;  // [1024][1024]
    unsigned short* a_pre   = xb;                        // alias (see above)

    conv_x<<<2048, 256, 0, stream>>>(x, xb);
    conv_t<<<dim3(96, 32), 256, 0, stream>>>(wqkv, wqkv_t, 3 * NX_);
    conv_t<<<dim3(32, 32), 256, 0, stream>>>(wpr, wproj_t, NX_);

    gemm_mfma<3 * NX_, 0><<<dim3(24, 32), 256, 0, stream>>>(
        xb, wqkv_t, bqkv, pk, pv, q_bf, k_bf, v_t, nullptr);
    attn_mfma<<<dim3(32 * 32), 256, 0, stream>>>(q_bf, k_bf, v_t, a_pre);
    gemm_mfma<NX_, 1><<<dim3(8, 32), 256, 0, stream>>>(
        a_pre, wproj_t, bpr, nullptr, nullptr, nullptr, nullptr, nullptr, a_out);
}

// Round 5
// 199.404 us; speedup vs baseline: 6.1852x; 1.0934x over previous
//
#include <hip/hip_runtime.h>
#include <cstddef>
#include <cstdint>

// GPT-style attention block on MI355X (gfx950), bf16-MFMA.
//   x:[B,N,NX] f32, c_attn_w:[NX,3NX] f32, c_attn_b, c_proj_w:[NX,NX], c_proj_b
//   outputs: a:[B,N,NX] f32, present:[2,B,H,N,hd] f32  (k then v)
// mask input (d_in[5]) ignored: causal mask applied analytically.
#define NX_ 1024
#define NH_ 16
#define HD_ 64
#define B_  2
#define N_  2048
#define M_  (B_ * N_)   // 4096

typedef __attribute__((ext_vector_type(8))) short bf16x8;   // 8 bf16 (4 VGPR)
typedef __attribute__((ext_vector_type(4))) float f32x4;

// fp32 -> bf16 round-to-nearest-even (cold paths)
__device__ __forceinline__ unsigned short f2bf(float f) {
    union { float f; unsigned u; } v; v.f = f;
    return (unsigned short)((v.u + 0x7FFFu + ((v.u >> 16) & 1u)) >> 16);
}
__device__ __forceinline__ unsigned pk2bf(float a, float b) {
    return (unsigned)f2bf(a) | ((unsigned)f2bf(b) << 16);
}
// hot-path pack: round-half-up + v_perm byte select (3 VALU ops)
__device__ __forceinline__ unsigned pkrnd(float a, float b) {
    union { float f; unsigned u; } ua, ub; ua.f = a; ub.f = b;
    return __builtin_amdgcn_perm(ub.u + 0x8000u, ua.u + 0x8000u, 0x07060302u);
}
// bare v_exp_f32 (2^x), bypasses libm fixup; saturates to 0 for very negative x
__device__ __forceinline__ float exp2_hw(float x) {
    float r;
    asm("v_exp_f32 %0, %1" : "=v"(r) : "v"(x));
    return r;
}

// async global->LDS, 16B per lane; LDS dest = wave-uniform base + lane*16
__device__ __forceinline__ void gload_lds16(const void* g, void* l) {
    __builtin_amdgcn_global_load_lds(
        (const __attribute__((address_space(1))) unsigned int*)g,
        (__attribute__((address_space(3))) unsigned int*)l, 16, 0, 0);
}

// ---------------------------------------------------------------------------
// Fused pre-pass (one launch): bid<2048: x f32->bf16; then wqkv / wproj
// f32 -> bf16 TRANSPOSED ([ncols][1024]) via 32x32 LDS tiles.
__global__ __launch_bounds__(256)
void pre_pass(const float* __restrict__ x, unsigned short* __restrict__ xb,
              const float* __restrict__ wqkv, unsigned short* __restrict__ wqkv_t,
              const float* __restrict__ wpr, unsigned short* __restrict__ wproj_t)
{
    const int bid = blockIdx.x, t = threadIdx.x;
    if (bid < 2048) {
        const size_t i = ((size_t)bid * 256 + t) * 8;
        const float4 a = *(const float4*)(x + i);
        const float4 b = *(const float4*)(x + i + 4);
        uint4 o;
        o.x = pk2bf(a.x, a.y); o.y = pk2bf(a.z, a.w);
        o.z = pk2bf(b.x, b.y); o.w = pk2bf(b.z, b.w);
        *(uint4*)(xb + i) = o;
        return;
    }
    __shared__ unsigned short tile[32][40];
    const float* W; unsigned short* Wt; int ncols, n0, k0;
    if (bid < 2048 + 3072) {
        const int b2 = bid - 2048;
        W = wqkv; Wt = wqkv_t; ncols = 3072; n0 = (b2 % 96) * 32; k0 = (b2 / 96) * 32;
    } else {
        const int b3 = bid - 5120;
        W = wpr; Wt = wproj_t; ncols = 1024; n0 = (b3 & 31) * 32; k0 = (b3 >> 5) * 32;
    }
    const int r = t >> 3, c4 = (t & 7) * 4;
    const float4 v = *(const float4*)(W + (size_t)(k0 + r) * ncols + n0 + c4);
    tile[r][c4 + 0] = f2bf(v.x); tile[r][c4 + 1] = f2bf(v.y);
    tile[r][c4 + 2] = f2bf(v.z); tile[r][c4 + 3] = f2bf(v.w);
    __syncthreads();
    uint2 o;
    o.x = (unsigned)tile[c4 + 0][r] | ((unsigned)tile[c4 + 1][r] << 16);
    o.y = (unsigned)tile[c4 + 2][r] | ((unsigned)tile[c4 + 3][r] << 16);
    *(uint2*)(Wt + (size_t)(n0 + r) * 1024 + k0 + c4) = o;
}

// ---------------------------------------------------------------------------
// m97-style bf16 GEMM: out = A[M,1024](bf16) @ Wt[NOUT,1024]^T(bf16) + bias.
// BM=BN=128, BK=32, 4 waves (2x2), 64x64/wave, dbuf LDS, global_load_lds
// staging with pre-swizzled global source (2-bit slot XOR). (Unchanged, r4-verified.)
template<int NOUT, int MODE>
__global__ __launch_bounds__(256, 3)
void gemm_mfma(const unsigned short* __restrict__ Ab, const unsigned short* __restrict__ Wt,
               const float* __restrict__ bias,
               float* __restrict__ o_pk, float* __restrict__ o_pv,
               unsigned short* __restrict__ o_q, unsigned short* __restrict__ o_k,
               unsigned short* __restrict__ o_vt, float* __restrict__ o_f)
{
    __shared__ __align__(16) unsigned short As[2][128 * 32];
    __shared__ __align__(16) unsigned short Bs[2][128 * 32];
    const int t = threadIdx.x, l = t & 63;
    const int g = l >> 4, q15 = l & 15;
    const int w = t >> 6, wm = w >> 1, wn = w & 1;
    const int m0 = blockIdx.y * 128, j0 = blockIdx.x * 128;

    f32x4 acc[4][4];
#pragma unroll
    for (int i = 0; i < 4; i++)
#pragma unroll
        for (int j = 0; j < 4; j++) { acc[i][j][0]=0.f; acc[i][j][1]=0.f; acc[i][j][2]=0.f; acc[i][j][3]=0.f; }

    const int srow[2] = { (w * 2 + 0) * 16 + (l >> 2), (w * 2 + 1) * 16 + (l >> 2) };
    const int kct0 = (l & 3) ^ (srow[0] & 3);
    const int kct1 = (l & 3) ^ (srow[1] & 3);

#define STAGE(BUF, K0)                                                          \
    do {                                                                        \
        gload_lds16(Ab + (size_t)(m0 + srow[0]) * 1024 + (K0) + kct0 * 8,       \
                    &As[BUF][(w * 2 + 0) * 64 * 8]);                            \
        gload_lds16(Ab + (size_t)(m0 + srow[1]) * 1024 + (K0) + kct1 * 8,       \
                    &As[BUF][(w * 2 + 1) * 64 * 8]);                            \
        gload_lds16(Wt + (size_t)(j0 + srow[0]) * 1024 + (K0) + kct0 * 8,       \
                    &Bs[BUF][(w * 2 + 0) * 64 * 8]);                            \
        gload_lds16(Wt + (size_t)(j0 + srow[1]) * 1024 + (K0) + kct1 * 8,       \
                    &Bs[BUF][(w * 2 + 1) * 64 * 8]);                            \
    } while (0)

    STAGE(0, 0);
    __syncthreads();

    for (int k0 = 0; k0 < 1024; k0 += 32) {
        const int buf = (k0 >> 5) & 1;
        if (k0 + 32 < 1024) STAGE(buf ^ 1, k0 + 32);

        bf16x8 af[4], bf[4];
#pragma unroll
        for (int mt = 0; mt < 4; mt++) {
            const int m = wm * 64 + mt * 16 + q15;
            af[mt] = *(const bf16x8*)&As[buf][m * 32 + ((g ^ (m & 3)) & 3) * 8];
        }
#pragma unroll
        for (int nt = 0; nt < 4; nt++) {
            const int n = wn * 64 + nt * 16 + q15;
            bf[nt] = *(const bf16x8*)&Bs[buf][n * 32 + ((g ^ (n & 3)) & 3) * 8];
        }
#pragma unroll
        for (int mt = 0; mt < 4; mt++)
#pragma unroll
            for (int nt = 0; nt < 4; nt++)
                acc[mt][nt] = __builtin_amdgcn_mfma_f32_16x16x32_bf16(af[mt], bf[nt], acc[mt][nt], 0, 0, 0);

        __syncthreads();
    }

#pragma unroll
    for (int nt = 0; nt < 4; nt++) {
        const int ncol = wn * 64 + nt * 16 + q15;
        const int jc = j0 + ncol;
        const float bz = bias[jc];
        const int sec = jc >> 10, jl = jc & 1023, hh = jl >> 6, dd = jl & 63;
#pragma unroll
        for (int mt = 0; mt < 4; mt++) {
#pragma unroll
            for (int r = 0; r < 4; r++) {
                const int m = m0 + wm * 64 + mt * 16 + g * 4 + r;
                const float val = acc[mt][nt][r] + bz;
                if (MODE == 1) {
                    o_f[(size_t)m * NOUT + jc] = val;
                } else {
                    const int bb = m >> 11, nn = m & 2047;
                    const int bhh = bb * NH_ + hh;
                    const size_t idx = ((size_t)bhh * N_ + nn) * HD_ + dd;
                    if (sec == 0)      o_q[idx] = f2bf(val * 0.18033688f); // 1/8 * log2(e)
                    else if (sec == 1) { o_pk[idx] = val; o_k[idx] = f2bf(val); }
                    else               { o_pv[idx] = val;
                                         o_vt[((size_t)bhh * HD_ + dd) * N_ + nn] = f2bf(val); }
                }
            }
        }
    }
#undef STAGE
}

// ---------------------------------------------------------------------------
// Flash attention, bf16 MFMA, FIXED-MAX softmax (no running max / no rescale):
// S bounded (|s|<~80 log2-domain) => exp2(s) cannot overflow fp32, and
// sum(exp2(s)*v)/sum(exp2(s)) is exactly softmax. Per-thread l partials are
// independent across tiles; cross-lane reduce deferred to after the loop.
// Swapped QK^T (S^T = K.Q^T) -> lane-local P; PV as O^T = V^T.P.
__global__ __launch_bounds__(256, 4)
void attn_mfma(const unsigned short* __restrict__ q_bf,
               const unsigned short* __restrict__ k_bf,
               const unsigned short* __restrict__ v_t,
               unsigned short* __restrict__ a_pre)
{
    __shared__ __align__(16) unsigned short Ks[2][64 * 64];
    __shared__ __align__(16) unsigned short Vt[2][64 * 64];
    __shared__ __align__(16) unsigned short Ps[64 * 64];

    const int t = threadIdx.x, l = t & 63, w = t >> 6;
    const int g = l >> 4, q15 = l & 15;
    const int bh = (int)blockIdx.x & 31;
    const int qt = 31 - ((int)blockIdx.x >> 5);   // LPT: heaviest q-tiles first
    const int b = bh >> 4, h = bh & 15;

    const unsigned short* kb  = k_bf + (size_t)bh * N_ * HD_;
    const unsigned short* vtb = v_t  + (size_t)bh * HD_ * N_;

    const int qrow = w * 16 + q15;
    const unsigned short* qp = q_bf + ((size_t)bh * N_ + (size_t)qt * 64 + qrow) * HD_ + g * 8;
    const bf16x8 qf0 = *(const bf16x8*)(qp);
    const bf16x8 qf1 = *(const bf16x8*)(qp + 32);

    const int sr = t >> 2, sc2 = (t & 3) * 2;
    uint4 stgK0, stgK1, stgV0, stgV1;

#define ISSUE(KT)                                                               \
    do {                                                                        \
        const uint4* ksrc = (const uint4*)(kb + ((size_t)((KT) * 64 + sr)) * HD_ + sc2 * 8); \
        stgK0 = ksrc[0]; stgK1 = ksrc[1];                                       \
        const uint4* vsrc = (const uint4*)(vtb + (size_t)sr * N_ + (KT) * 64 + sc2 * 8);     \
        stgV0 = vsrc[0]; stgV1 = vsrc[1];                                       \
    } while (0)

#define COMMIT(BUF)                                                             \
    do {                                                                        \
        unsigned short* kd = &Ks[BUF][sr * 64];                                 \
        *(uint4*)&kd[((sc2 ^ (sr & 7)) & 7) * 8]       = stgK0;                 \
        *(uint4*)&kd[(((sc2 + 1) ^ (sr & 7)) & 7) * 8] = stgK1;                 \
        unsigned short* vd = &Vt[BUF][sr * 64];                                 \
        *(uint4*)&vd[((sc2 ^ (sr & 7)) & 7) * 8]       = stgV0;                 \
        *(uint4*)&vd[(((sc2 + 1) ^ (sr & 7)) & 7) * 8] = stgV1;                 \
    } while (0)

    ISSUE(0); COMMIT(0);
    __syncthreads();

    float l_i = 0.f;
    f32x4 oacc[4];
#pragma unroll
    for (int i = 0; i < 4; i++) { oacc[i][0]=0.f; oacc[i][1]=0.f; oacc[i][2]=0.f; oacc[i][3]=0.f; }

    int cur = 0;
    char* const prow = (char*)Ps + qrow * 128;
    const int psw = (qrow & 7) << 4;

    for (int kt = 0; kt <= qt; kt++) {
        const bool more = (kt < qt);
        if (more) ISSUE(kt + 1);                  // T14: issue next tile early

        // ---- S^T = K . Q^T
        f32x4 sacc[4];
#pragma unroll
        for (int i = 0; i < 4; i++) { sacc[i][0]=0.f; sacc[i][1]=0.f; sacc[i][2]=0.f; sacc[i][3]=0.f; }
        __builtin_amdgcn_s_setprio(1);
#pragma unroll
        for (int kt4 = 0; kt4 < 4; kt4++) {
            const int row = kt4 * 16 + q15;
            const bf16x8 kf0 = *(const bf16x8*)&Ks[cur][row * 64 + ((g ^ (row & 7)) & 7) * 8];
            sacc[kt4] = __builtin_amdgcn_mfma_f32_16x16x32_bf16(kf0, qf0, sacc[kt4], 0, 0, 0);
            const bf16x8 kf1 = *(const bf16x8*)&Ks[cur][row * 64 + (((g + 4) ^ (row & 7)) & 7) * 8];
            sacc[kt4] = __builtin_amdgcn_mfma_f32_16x16x32_bf16(kf1, qf1, sacc[kt4], 0, 0, 0);
        }
        __builtin_amdgcn_s_setprio(0);

        // ---- P = exp2(S), per-thread partial sum, bf16 pack into private Ps rows
        float pe[16];
        if (kt == qt) {   // diagonal tile: mask kc > q  (exp2(-1e30) -> 0)
#pragma unroll
            for (int kt4 = 0; kt4 < 4; kt4++)
#pragma unroll
                for (int r = 0; r < 4; r++) {
                    const float s = (kt4 * 16 + g * 4 + r > qrow) ? -1.0e30f : sacc[kt4][r];
                    pe[kt4 * 4 + r] = exp2_hw(s);
                }
        } else {
#pragma unroll
            for (int kt4 = 0; kt4 < 4; kt4++)
#pragma unroll
                for (int r = 0; r < 4; r++) pe[kt4 * 4 + r] = exp2_hw(sacc[kt4][r]);
        }
        {   // tree-sum of the 16 partials (depth 4)
            float s8[8];
#pragma unroll
            for (int i = 0; i < 8; i++) s8[i] = pe[2 * i] + pe[2 * i + 1];
            const float s0 = (s8[0] + s8[1]) + (s8[2] + s8[3]);
            const float s1 = (s8[4] + s8[5]) + (s8[6] + s8[7]);
            l_i += s0 + s1;
        }
#pragma unroll
        for (int kt4 = 0; kt4 < 4; kt4++) {
            uint2 w2;
            w2.x = pkrnd(pe[kt4 * 4 + 0], pe[kt4 * 4 + 1]);
            w2.y = pkrnd(pe[kt4 * 4 + 2], pe[kt4 * 4 + 3]);
            *(uint2*)(prow + ((kt4 * 32 + g * 8) ^ psw)) = w2;   // 8B, 16B-slot XOR keeps align
        }

        // ---- O^T += V^T . P
        {
            const bf16x8 pf0 = *(const bf16x8*)(prow + ((g * 16) ^ psw));
            const bf16x8 pf1 = *(const bf16x8*)(prow + (((g + 4) * 16) ^ psw));
            __builtin_amdgcn_s_setprio(1);
#pragma unroll
            for (int dt = 0; dt < 4; dt++) {
                const int vrow = dt * 16 + q15;
                const bf16x8 vf = *(const bf16x8*)&Vt[cur][vrow * 64 + ((g ^ (vrow & 7)) & 7) * 8];
                oacc[dt] = __builtin_amdgcn_mfma_f32_16x16x32_bf16(vf, pf0, oacc[dt], 0, 0, 0);
            }
#pragma unroll
            for (int dt = 0; dt < 4; dt++) {
                const int vrow = dt * 16 + q15;
                const bf16x8 vf = *(const bf16x8*)&Vt[cur][vrow * 64 + (((g + 4) ^ (vrow & 7)) & 7) * 8];
                oacc[dt] = __builtin_amdgcn_mfma_f32_16x16x32_bf16(vf, pf1, oacc[dt], 0, 0, 0);
            }
            __builtin_amdgcn_s_setprio(0);
        }

        if (more) COMMIT(cur ^ 1);                // write next tile late
        __syncthreads();
        cur ^= 1;
    }

    // deferred cross-lane l reduce (lanes l, l^16, l^32 share the q-column)
    float lt = l_i;
    lt += __shfl_xor(lt, 16);
    lt += __shfl_xor(lt, 32);
    const float inv = 1.0f / lt;

    unsigned short* ap2 = a_pre + ((size_t)(b * N_ + qt * 64 + qrow)) * NX_ + h * 64;
#pragma unroll
    for (int dt = 0; dt < 4; dt++) {
#pragma unroll
        for (int j2 = 0; j2 < 2; j2++) {
            const int d = dt * 16 + g * 4 + j2 * 2;
            *(unsigned*)(ap2 + d) = pkrnd(oacc[dt][j2 * 2] * inv, oacc[dt][j2 * 2 + 1] * inv);
        }
    }
#undef ISSUE
#undef COMMIT
}

// ---------------------------------------------------------------------------
extern "C" void kernel_launch(void* const* d_in, const int* in_sizes, int n_in,
                              void* d_out, int out_size, void* d_ws, size_t ws_size,
                              hipStream_t stream)
{
    (void)in_sizes; (void)n_in; (void)out_size; (void)ws_size;
    const float* x    = (const float*)d_in[0];
    const float* wqkv = (const float*)d_in[1];
    const float* bqkv = (const float*)d_in[2];
    const float* wpr  = (const float*)d_in[3];
    const float* bpr  = (const float*)d_in[4];
    // d_in[5] (mask) ignored: causal mask applied analytically.

    float* out   = (float*)d_out;
    float* a_out = out;                                  // [B,N,NX] f32
    float* pk    = out + (size_t)M_ * NX_;               // present[0]: k [B,H,N,hd]
    float* pv    = pk + (size_t)B_ * NH_ * N_ * HD_;     // present[1]: v

    // workspace (40 MB): bf16 x / q / k / v^T / transposed weights.
    // a_pre aliases xb: xb fully consumed by qkv GEMM before attn writes.
    const size_t SEG = (size_t)M_ * NX_;                 // 4M elems
    unsigned short* xb      = (unsigned short*)d_ws;     // [4096][1024]
    unsigned short* q_bf    = xb + SEG;                  // [bh][n][d]
    unsigned short* k_bf    = q_bf + SEG;                // [bh][n][d]
    unsigned short* v_t     = k_bf + SEG;                // [bh][d][n]
    unsigned short* wqkv_t  = v_t + SEG;                 // [3072][1024]
    unsigned short* wproj_t = wqkv_t + (size_t)3 * NX_ * NX_;  // [1024][1024]
    unsigned short* a_pre   = xb;                        // alias (see above)

    pre_pass<<<2048 + 3072 + 1024, 256, 0, stream>>>(x, xb, wqkv, wqkv_t, wpr, wproj_t);

    gemm_mfma<3 * NX_, 0><<<dim3(24, 32), 256, 0, stream>>>(
        xb, wqkv_t, bqkv, pk, pv, q_bf, k_bf, v_t, nullptr);
    attn_mfma<<<dim3(32 * 32), 256, 0, stream>>>(q_bf, k_bf, v_t, a_pre);
    gemm_mfma<NX_, 1><<<dim3(8, 32), 256, 0, stream>>>(
        a_pre, wproj_t, bpr, nullptr, nullptr, nullptr, nullptr, nullptr, a_out);
}

// Round 6
// 198.780 us; speedup vs baseline: 6.2047x; 1.0031x over previous
//
#include <hip/hip_runtime.h>
#include <cstddef>
#include <cstdint>

// GPT-style attention block on MI355X (gfx950), bf16-MFMA.
//   x:[B,N,NX] f32, c_attn_w:[NX,3NX] f32, c_attn_b, c_proj_w:[NX,NX], c_proj_b
//   outputs: a:[B,N,NX] f32, present:[2,B,H,N,hd] f32  (k then v)
// mask input (d_in[5]) ignored: causal mask applied analytically.
#define NX_ 1024
#define NH_ 16
#define HD_ 64
#define B_  2
#define N_  2048
#define M_  (B_ * N_)   // 4096

typedef __attribute__((ext_vector_type(8))) short bf16x8;   // 8 bf16 (4 VGPR)
typedef __attribute__((ext_vector_type(4))) float f32x4;

// fp32 -> bf16 round-to-nearest-even (cold paths)
__device__ __forceinline__ unsigned short f2bf(float f) {
    union { float f; unsigned u; } v; v.f = f;
    return (unsigned short)((v.u + 0x7FFFu + ((v.u >> 16) & 1u)) >> 16);
}
__device__ __forceinline__ unsigned pk2bf(float a, float b) {
    return (unsigned)f2bf(a) | ((unsigned)f2bf(b) << 16);
}
// hot-path pack: round-half-up + v_perm byte select (3 VALU ops)
__device__ __forceinline__ unsigned pkrnd(float a, float b) {
    union { float f; unsigned u; } ua, ub; ua.f = a; ub.f = b;
    return __builtin_amdgcn_perm(ub.u + 0x8000u, ua.u + 0x8000u, 0x07060302u);
}
// bare v_exp_f32 (2^x), bypasses libm fixup; flushes to 0 for very negative x
__device__ __forceinline__ float exp2_hw(float x) {
    float r;
    asm("v_exp_f32 %0, %1" : "=v"(r) : "v"(x));
    return r;
}

// async global->LDS, 16B per lane; LDS dest = wave-uniform base + lane*16
__device__ __forceinline__ void gload_lds16(const void* g, void* l) {
    __builtin_amdgcn_global_load_lds(
        (const __attribute__((address_space(1))) unsigned int*)g,
        (__attribute__((address_space(3))) unsigned int*)l, 16, 0, 0);
}

// ---------------------------------------------------------------------------
// Fused pre-pass (one launch): bid<2048: x f32->bf16; then wqkv / wproj
// f32 -> bf16 TRANSPOSED ([ncols][1024]) via 32x32 LDS tiles.
__global__ __launch_bounds__(256)
void pre_pass(const float* __restrict__ x, unsigned short* __restrict__ xb,
              const float* __restrict__ wqkv, unsigned short* __restrict__ wqkv_t,
              const float* __restrict__ wpr, unsigned short* __restrict__ wproj_t)
{
    const int bid = blockIdx.x, t = threadIdx.x;
    if (bid < 2048) {
        const size_t i = ((size_t)bid * 256 + t) * 8;
        const float4 a = *(const float4*)(x + i);
        const float4 b = *(const float4*)(x + i + 4);
        uint4 o;
        o.x = pk2bf(a.x, a.y); o.y = pk2bf(a.z, a.w);
        o.z = pk2bf(b.x, b.y); o.w = pk2bf(b.z, b.w);
        *(uint4*)(xb + i) = o;
        return;
    }
    __shared__ unsigned short tile[32][40];
    const float* W; unsigned short* Wt; int ncols, n0, k0;
    if (bid < 2048 + 3072) {
        const int b2 = bid - 2048;
        W = wqkv; Wt = wqkv_t; ncols = 3072; n0 = (b2 % 96) * 32; k0 = (b2 / 96) * 32;
    } else {
        const int b3 = bid - 5120;
        W = wpr; Wt = wproj_t; ncols = 1024; n0 = (b3 & 31) * 32; k0 = (b3 >> 5) * 32;
    }
    const int r = t >> 3, c4 = (t & 7) * 4;
    const float4 v = *(const float4*)(W + (size_t)(k0 + r) * ncols + n0 + c4);
    tile[r][c4 + 0] = f2bf(v.x); tile[r][c4 + 1] = f2bf(v.y);
    tile[r][c4 + 2] = f2bf(v.z); tile[r][c4 + 3] = f2bf(v.w);
    __syncthreads();
    uint2 o;
    o.x = (unsigned)tile[c4 + 0][r] | ((unsigned)tile[c4 + 1][r] << 16);
    o.y = (unsigned)tile[c4 + 2][r] | ((unsigned)tile[c4 + 3][r] << 16);
    *(uint2*)(Wt + (size_t)(n0 + r) * 1024 + k0 + c4) = o;
}

// ---------------------------------------------------------------------------
// m97-style bf16 GEMM: out = A[M,1024](bf16) @ Wt[NOUT,1024]^T(bf16) + bias.
// BM=BN=128, BK=32, 4 waves (2x2), 64x64/wave, dbuf LDS, global_load_lds
// staging with pre-swizzled global source.
// Swizzle: C(row) = (row&3)^((row>>2)&3) -> fragment-group reads are 2-way
// (free) instead of 4-way (r5 counter evidence: 3.1M conflicts/dispatch).
// 1D grid + bijective XCD swizzle (T1), bx-fast within each XCD chunk.
// GX = grid cols (NOUT/128). MODE 0 (qkv scatter) / MODE 1 (proj plain).
template<int NOUT, int MODE, int GX>
__global__ __launch_bounds__(256, 3)
void gemm_mfma(const unsigned short* __restrict__ Ab, const unsigned short* __restrict__ Wt,
               const float* __restrict__ bias,
               float* __restrict__ o_pk, float* __restrict__ o_pv,
               unsigned short* __restrict__ o_q, unsigned short* __restrict__ o_k,
               unsigned short* __restrict__ o_vt, float* __restrict__ o_f)
{
    __shared__ __align__(16) unsigned short As[2][128 * 32];
    __shared__ __align__(16) unsigned short Bs[2][128 * 32];
    const int t = threadIdx.x, l = t & 63;
    const int g = l >> 4, q15 = l & 15;
    const int w = t >> 6, wm = w >> 1, wn = w & 1;

    // bijective XCD swizzle: nwg = GX*32, nwg%8==0
    const int nwg = GX * 32;
    const int swz = ((int)blockIdx.x & 7) * (nwg / 8) + ((int)blockIdx.x >> 3);
    const int m0 = (swz / GX) * 128, j0 = (swz % GX) * 128;

    f32x4 acc[4][4];
#pragma unroll
    for (int i = 0; i < 4; i++)
#pragma unroll
        for (int j = 0; j < 4; j++) { acc[i][j][0]=0.f; acc[i][j][1]=0.f; acc[i][j][2]=0.f; acc[i][j][3]=0.f; }

    const int srow[2] = { (w * 2 + 0) * 16 + (l >> 2), (w * 2 + 1) * 16 + (l >> 2) };
    const int kct0 = ((l & 3) ^ (srow[0] & 3) ^ ((srow[0] >> 2) & 3)) & 3;
    const int kct1 = ((l & 3) ^ (srow[1] & 3) ^ ((srow[1] >> 2) & 3)) & 3;

#define STAGE(BUF, K0)                                                          \
    do {                                                                        \
        gload_lds16(Ab + (size_t)(m0 + srow[0]) * 1024 + (K0) + kct0 * 8,       \
                    &As[BUF][(w * 2 + 0) * 64 * 8]);                            \
        gload_lds16(Ab + (size_t)(m0 + srow[1]) * 1024 + (K0) + kct1 * 8,       \
                    &As[BUF][(w * 2 + 1) * 64 * 8]);                            \
        gload_lds16(Wt + (size_t)(j0 + srow[0]) * 1024 + (K0) + kct0 * 8,       \
                    &Bs[BUF][(w * 2 + 0) * 64 * 8]);                            \
        gload_lds16(Wt + (size_t)(j0 + srow[1]) * 1024 + (K0) + kct1 * 8,       \
                    &Bs[BUF][(w * 2 + 1) * 64 * 8]);                            \
    } while (0)

    STAGE(0, 0);
    __syncthreads();

    for (int k0 = 0; k0 < 1024; k0 += 32) {
        const int buf = (k0 >> 5) & 1;
        if (k0 + 32 < 1024) STAGE(buf ^ 1, k0 + 32);

        bf16x8 af[4], bf[4];
#pragma unroll
        for (int mt = 0; mt < 4; mt++) {
            const int m = wm * 64 + mt * 16 + q15;
            af[mt] = *(const bf16x8*)&As[buf][m * 32 + ((g ^ (m & 3) ^ ((m >> 2) & 3)) & 3) * 8];
        }
#pragma unroll
        for (int nt = 0; nt < 4; nt++) {
            const int n = wn * 64 + nt * 16 + q15;
            bf[nt] = *(const bf16x8*)&Bs[buf][n * 32 + ((g ^ (n & 3) ^ ((n >> 2) & 3)) & 3) * 8];
        }
#pragma unroll
        for (int mt = 0; mt < 4; mt++)
#pragma unroll
            for (int nt = 0; nt < 4; nt++)
                acc[mt][nt] = __builtin_amdgcn_mfma_f32_16x16x32_bf16(af[mt], bf[nt], acc[mt][nt], 0, 0, 0);

        __syncthreads();
    }

#pragma unroll
    for (int nt = 0; nt < 4; nt++) {
        const int ncol = wn * 64 + nt * 16 + q15;
        const int jc = j0 + ncol;
        const float bz = bias[jc];
        const int sec = jc >> 10, jl = jc & 1023, hh = jl >> 6, dd = jl & 63;
#pragma unroll
        for (int mt = 0; mt < 4; mt++) {
#pragma unroll
            for (int r = 0; r < 4; r++) {
                const int m = m0 + wm * 64 + mt * 16 + g * 4 + r;
                const float val = acc[mt][nt][r] + bz;
                if (MODE == 1) {
                    o_f[(size_t)m * NOUT + jc] = val;
                } else {
                    const int bb = m >> 11, nn = m & 2047;
                    const int bhh = bb * NH_ + hh;
                    const size_t idx = ((size_t)bhh * N_ + nn) * HD_ + dd;
                    if (sec == 0)      o_q[idx] = f2bf(val * 0.18033688f); // 1/8 * log2(e)
                    else if (sec == 1) { o_pk[idx] = val; o_k[idx] = f2bf(val); }
                    else               { o_pv[idx] = val;
                                         o_vt[((size_t)bhh * HD_ + dd) * N_ + nn] = f2bf(val); }
                }
            }
        }
    }
#undef STAGE
}

// ---------------------------------------------------------------------------
// Flash attention, bf16 MFMA, fixed-max softmax. QBLK=128 (8 waves x 16 rows):
// halves K/V staging events and barrier-drains per unit work vs QBLK=64.
// Swapped QK^T (S^T = K.Q^T) -> lane-local P; PV as O^T = V^T.P.
// Grid 512 (all co-resident): bh grouped per XCD (2MB K/V set fits L2);
// qt sequence pairs heavy+light tiles on the same CU.
__global__ __launch_bounds__(512, 2)
void attn_mfma(const unsigned short* __restrict__ q_bf,
               const unsigned short* __restrict__ k_bf,
               const unsigned short* __restrict__ v_t,
               unsigned short* __restrict__ a_pre)
{
    __shared__ __align__(16) unsigned short Ks[2][64 * 64];
    __shared__ __align__(16) unsigned short Vt[2][64 * 64];
    __shared__ __align__(16) unsigned short Ps[128 * 64];

    const int t = threadIdx.x, l = t & 63, w = t >> 6;   // w: 0..7
    const int g = l >> 4, q15 = l & 15;

    // block decode: xcd chunk = fixed 4 heads; qt pairing j/(j+8) sums const
    const int bid = (int)blockIdx.x;
    const int x = bid & 7, r = bid >> 3;                 // r: 0..63
    const int bh = x * 4 + (r & 3);
    const int j = r >> 2;                                // 0..15
    const int qt = (j < 8) ? (15 - j) : (j - 8);
    const int b = bh >> 4, h = bh & 15;

    const unsigned short* kb  = k_bf + (size_t)bh * N_ * HD_;
    const unsigned short* vtb = v_t  + (size_t)bh * HD_ * N_;

    const int qrow = w * 16 + q15;                       // 0..127
    const int qg = qt * 128 + qrow;                      // global q row
    const unsigned short* qp = q_bf + ((size_t)bh * N_ + qg) * HD_ + g * 8;
    const bf16x8 qf0 = *(const bf16x8*)(qp);
    const bf16x8 qf1 = *(const bf16x8*)(qp + 32);

    // staging: 512 thr, 1 uint4 each per matrix: row sr (0..63), slot s8 (0..7)
    const int sr = t >> 3, s8 = t & 7;
    uint4 stgK, stgV;

#define ISSUE(KT)                                                               \
    do {                                                                        \
        stgK = *(const uint4*)(kb + ((size_t)((KT) * 64 + sr)) * HD_ + s8 * 8); \
        stgV = *(const uint4*)(vtb + (size_t)sr * N_ + (KT) * 64 + s8 * 8);     \
    } while (0)

#define COMMIT(BUF)                                                             \
    do {                                                                        \
        *(uint4*)&Ks[BUF][sr * 64 + ((s8 ^ (sr & 7)) & 7) * 8] = stgK;          \
        *(uint4*)&Vt[BUF][sr * 64 + ((s8 ^ (sr & 7)) & 7) * 8] = stgV;          \
    } while (0)

    ISSUE(0); COMMIT(0);
    __syncthreads();

    float l_i = 0.f;
    f32x4 oacc[4];
#pragma unroll
    for (int i = 0; i < 4; i++) { oacc[i][0]=0.f; oacc[i][1]=0.f; oacc[i][2]=0.f; oacc[i][3]=0.f; }

    int cur = 0;
    char* const prow = (char*)Ps + qrow * 128;
    const int psw = (qrow & 7) << 4;
    const int ktmax = 2 * qt + 1;

    for (int kt = 0; kt <= ktmax; kt++) {
        const bool more = (kt < ktmax);
        if (more) ISSUE(kt + 1);                  // T14: issue next tile early

        // ---- S^T = K . Q^T
        f32x4 sacc[4];
#pragma unroll
        for (int i = 0; i < 4; i++) { sacc[i][0]=0.f; sacc[i][1]=0.f; sacc[i][2]=0.f; sacc[i][3]=0.f; }
        __builtin_amdgcn_s_setprio(1);
#pragma unroll
        for (int kt4 = 0; kt4 < 4; kt4++) {
            const int row = kt4 * 16 + q15;
            const bf16x8 kf0 = *(const bf16x8*)&Ks[cur][row * 64 + ((g ^ (row & 7)) & 7) * 8];
            sacc[kt4] = __builtin_amdgcn_mfma_f32_16x16x32_bf16(kf0, qf0, sacc[kt4], 0, 0, 0);
            const bf16x8 kf1 = *(const bf16x8*)&Ks[cur][row * 64 + (((g + 4) ^ (row & 7)) & 7) * 8];
            sacc[kt4] = __builtin_amdgcn_mfma_f32_16x16x32_bf16(kf1, qf1, sacc[kt4], 0, 0, 0);
        }
        __builtin_amdgcn_s_setprio(0);

        // ---- P = exp2(S), per-thread partial sum, bf16 pack into private Ps rows
        float pe[16];
        if (kt >= 2 * qt) {   // diagonal region: mask global kc > global q
#pragma unroll
            for (int kt4 = 0; kt4 < 4; kt4++)
#pragma unroll
                for (int rr = 0; rr < 4; rr++) {
                    const int kcg = kt * 64 + kt4 * 16 + g * 4 + rr;
                    const float s = (kcg > qg) ? -1.0e30f : sacc[kt4][rr];
                    pe[kt4 * 4 + rr] = exp2_hw(s);
                }
        } else {
#pragma unroll
            for (int kt4 = 0; kt4 < 4; kt4++)
#pragma unroll
                for (int rr = 0; rr < 4; rr++) pe[kt4 * 4 + rr] = exp2_hw(sacc[kt4][rr]);
        }
        {   // tree-sum of the 16 partials (depth 4)
            float s8v[8];
#pragma unroll
            for (int i = 0; i < 8; i++) s8v[i] = pe[2 * i] + pe[2 * i + 1];
            const float s0 = (s8v[0] + s8v[1]) + (s8v[2] + s8v[3]);
            const float s1 = (s8v[4] + s8v[5]) + (s8v[6] + s8v[7]);
            l_i += s0 + s1;
        }
#pragma unroll
        for (int kt4 = 0; kt4 < 4; kt4++) {
            uint2 w2;
            w2.x = pkrnd(pe[kt4 * 4 + 0], pe[kt4 * 4 + 1]);
            w2.y = pkrnd(pe[kt4 * 4 + 2], pe[kt4 * 4 + 3]);
            *(uint2*)(prow + ((kt4 * 32 + g * 8) ^ psw)) = w2;
        }

        // ---- O^T += V^T . P
        {
            const bf16x8 pf0 = *(const bf16x8*)(prow + ((g * 16) ^ psw));
            const bf16x8 pf1 = *(const bf16x8*)(prow + (((g + 4) * 16) ^ psw));
            __builtin_amdgcn_s_setprio(1);
#pragma unroll
            for (int dt = 0; dt < 4; dt++) {
                const int vrow = dt * 16 + q15;
                const bf16x8 vf = *(const bf16x8*)&Vt[cur][vrow * 64 + ((g ^ (vrow & 7)) & 7) * 8];
                oacc[dt] = __builtin_amdgcn_mfma_f32_16x16x32_bf16(vf, pf0, oacc[dt], 0, 0, 0);
            }
#pragma unroll
            for (int dt = 0; dt < 4; dt++) {
                const int vrow = dt * 16 + q15;
                const bf16x8 vf = *(const bf16x8*)&Vt[cur][vrow * 64 + (((g + 4) ^ (vrow & 7)) & 7) * 8];
                oacc[dt] = __builtin_amdgcn_mfma_f32_16x16x32_bf16(vf, pf1, oacc[dt], 0, 0, 0);
            }
            __builtin_amdgcn_s_setprio(0);
        }

        if (more) COMMIT(cur ^ 1);                // write next tile late
        __syncthreads();
        cur ^= 1;
    }

    // deferred cross-lane l reduce (lanes l, l^16, l^32 share the q-column)
    float lt = l_i;
    lt += __shfl_xor(lt, 16);
    lt += __shfl_xor(lt, 32);
    const float inv = 1.0f / lt;

    unsigned short* ap2 = a_pre + ((size_t)(b * N_ + qg)) * NX_ + h * 64;
#pragma unroll
    for (int dt = 0; dt < 4; dt++) {
#pragma unroll
        for (int j2 = 0; j2 < 2; j2++) {
            const int d = dt * 16 + g * 4 + j2 * 2;
            *(unsigned*)(ap2 + d) = pkrnd(oacc[dt][j2 * 2] * inv, oacc[dt][j2 * 2 + 1] * inv);
        }
    }
#undef ISSUE
#undef COMMIT
}

// ---------------------------------------------------------------------------
extern "C" void kernel_launch(void* const* d_in, const int* in_sizes, int n_in,
                              void* d_out, int out_size, void* d_ws, size_t ws_size,
                              hipStream_t stream)
{
    (void)in_sizes; (void)n_in; (void)out_size; (void)ws_size;
    const float* x    = (const float*)d_in[0];
    const float* wqkv = (const float*)d_in[1];
    const float* bqkv = (const float*)d_in[2];
    const float* wpr  = (const float*)d_in[3];
    const float* bpr  = (const float*)d_in[4];
    // d_in[5] (mask) ignored: causal mask applied analytically.

    float* out   = (float*)d_out;
    float* a_out = out;                                  // [B,N,NX] f32
    float* pk    = out + (size_t)M_ * NX_;               // present[0]: k [B,H,N,hd]
    float* pv    = pk + (size_t)B_ * NH_ * N_ * HD_;     // present[1]: v

    // workspace (40 MB): bf16 x / q / k / v^T / transposed weights.
    // a_pre aliases xb: xb fully consumed by qkv GEMM before attn writes.
    const size_t SEG = (size_t)M_ * NX_;                 // 4M elems
    unsigned short* xb      = (unsigned short*)d_ws;     // [4096][1024]
    unsigned short* q_bf    = xb + SEG;                  // [bh][n][d]
    unsigned short* k_bf    = q_bf + SEG;                // [bh][n][d]
    unsigned short* v_t     = k_bf + SEG;                // [bh][d][n]
    unsigned short* wqkv_t  = v_t + SEG;                 // [3072][1024]
    unsigned short* wproj_t = wqkv_t + (size_t)3 * NX_ * NX_;  // [1024][1024]
    unsigned short* a_pre   = xb;                        // alias (see above)

    pre_pass<<<2048 + 3072 + 1024, 256, 0, stream>>>(x, xb, wqkv, wqkv_t, wpr, wproj_t);

    gemm_mfma<3 * NX_, 0, 24><<<768, 256, 0, stream>>>(
        xb, wqkv_t, bqkv, pk, pv, q_bf, k_bf, v_t, nullptr);
    attn_mfma<<<512, 512, 0, stream>>>(q_bf, k_bf, v_t, a_pre);
    gemm_mfma<NX_, 1, 8><<<256, 256, 0, stream>>>(
        a_pre, wproj_t, bpr, nullptr, nullptr, nullptr, nullptr, nullptr, a_out);
}